// Round 5
// baseline (124.340 us; speedup 1.0000x reference)
//
#include <hip/hip_runtime.h>

// ---------------- types ----------------
typedef __attribute__((ext_vector_type(8))) short bf16x8;   // 8 bf16 in 4 VGPRs
typedef __attribute__((ext_vector_type(4))) float f32x4;
typedef __attribute__((ext_vector_type(8))) unsigned short us8;

#define K_DIM 2048
#define QK_N  320     // 256 q cols + 64 k cols
#define SEQ   4096
#define BK    64
#define NCHUNK 32                      // K_DIM / BK
#define NHALF  160                     // N columns per block
#define BCHUNK 20480                   // bytes of one B chunk: 8 units * 160 cols * 16B

__device__ __forceinline__ unsigned short f2bf(float f) {
    unsigned int u = __builtin_bit_cast(unsigned int, f);
    u += 0x7FFFu + ((u >> 16) & 1u);      // round-to-nearest-even
    return (unsigned short)(u >> 16);
}

// ---------------- W convert + re-layout ----------------
// ws layout: [2 N-halves][NCHUNK][8 k-units][160 cols][16B]
// (a lane's 16B fragment for (k-unit, col) is one contiguous b128; 16
// consecutive cols = 256B contiguous -> perfectly coalesced frag loads)
__global__ void cvt_w_swz(const float* __restrict__ Wq,
                          const float* __restrict__ Wk,
                          unsigned short* __restrict__ ws) {
    int id = blockIdx.x * 256 + threadIdx.x;   // 320*256 ids
    int c  = id >> 8;                          // 0..319 (output col)
    int k8 = id & 255;                         // 8-elem k group
    int k0 = k8 * 8;
    const float* src = (c < 256) ? (Wq + (size_t)c * K_DIM + k0)
                                 : (Wk + (size_t)(c - 256) * K_DIM + k0);
    float4 v0 = *reinterpret_cast<const float4*>(src);
    float4 v1 = *reinterpret_cast<const float4*>(src + 4);
    us8 o;
    o[0] = f2bf(v0.x); o[1] = f2bf(v0.y); o[2] = f2bf(v0.z); o[3] = f2bf(v0.w);
    o[4] = f2bf(v1.x); o[5] = f2bf(v1.y); o[6] = f2bf(v1.z); o[7] = f2bf(v1.w);
    int half = (c >= NHALF) ? 1 : 0;
    int cc   = c - half * NHALF;
    int kc = k0 / BK;            // chunk index 0..31
    int u  = (k0 % BK) >> 3;     // k-unit within chunk (0..7)
    size_t byteoff = (size_t)half * (NCHUNK * (size_t)BCHUNK)
                   + (size_t)kc * BCHUNK + ((size_t)(u * NHALF + cc) * 16);
    *reinterpret_cast<us8*>((char*)ws + byteoff) = o;
}

// ---------------- projection GEMM: C[8192][320] = h[8192][2048](fp32) * W^T ----
// scores-style: NO LDS, NO barriers. grid (2 N-halves, 256 M-strips) x 256
// threads (4 waves: 2 rg x 2 cg). block tile 32x160; wave tile 16x80.
// A-frags direct from fp32 h (cvt in-reg); B-frags direct from pre-swizzled
// W (L2-resident). TLP + compiler pipelining hide latency — no sync points.
__global__ __launch_bounds__(256) void proj_gemm(
    const float* __restrict__ A,            // h fp32 [8192][2048]
    const unsigned short* __restrict__ Wsz, // re-laid-out W
    unsigned short* __restrict__ C)         // [8192][320] bf16
{
    const int tid  = threadIdx.x;
    const int lane = tid & 63;
    const int wid  = tid >> 6;          // 0..3
    const int rg   = wid >> 1;          // 0..1 (M row-group)
    const int cg   = wid & 1;           // 0..1 (N col-group)
    const int half = blockIdx.x;
    const int row0 = blockIdx.y * 32 + rg * 16;
    const int lr = lane & 15, lg = lane >> 4;

    const float* ap = A + (size_t)(row0 + lr) * K_DIM + lg * 8;
    const char* wbase = (const char*)Wsz + (size_t)half * (NCHUNK * (size_t)BCHUNK)
                      + ((cg * 80 + lr) << 4);

    f32x4 acc[5];
#pragma unroll
    for (int j = 0; j < 5; ++j) acc[j] = (f32x4)0.f;

#pragma unroll 2
    for (int t = 0; t < 64; ++t) {
        // B fragments: chunk t>>1, k-units ((t&1)*4 + lg)
        const char* bu = wbase + (size_t)(t >> 1) * BCHUNK
                       + (size_t)(((t & 1) * 4 + lg) * NHALF) * 16;
        bf16x8 b0 = *reinterpret_cast<const bf16x8*>(bu);
        bf16x8 b1 = *reinterpret_cast<const bf16x8*>(bu + 256);
        bf16x8 b2 = *reinterpret_cast<const bf16x8*>(bu + 512);
        bf16x8 b3 = *reinterpret_cast<const bf16x8*>(bu + 768);
        bf16x8 b4 = *reinterpret_cast<const bf16x8*>(bu + 1024);
        // A fragment: 32B contiguous fp32 -> 8 bf16
        const float* p = ap + t * 32;
        float4 x = *reinterpret_cast<const float4*>(p);
        float4 y = *reinterpret_cast<const float4*>(p + 4);
        bf16x8 a;
        a[0] = (short)f2bf(x.x); a[1] = (short)f2bf(x.y);
        a[2] = (short)f2bf(x.z); a[3] = (short)f2bf(x.w);
        a[4] = (short)f2bf(y.x); a[5] = (short)f2bf(y.y);
        a[6] = (short)f2bf(y.z); a[7] = (short)f2bf(y.w);
        acc[0] = __builtin_amdgcn_mfma_f32_16x16x32_bf16(a, b0, acc[0], 0, 0, 0);
        acc[1] = __builtin_amdgcn_mfma_f32_16x16x32_bf16(a, b1, acc[1], 0, 0, 0);
        acc[2] = __builtin_amdgcn_mfma_f32_16x16x32_bf16(a, b2, acc[2], 0, 0, 0);
        acc[3] = __builtin_amdgcn_mfma_f32_16x16x32_bf16(a, b3, acc[3], 0, 0, 0);
        acc[4] = __builtin_amdgcn_mfma_f32_16x16x32_bf16(a, b4, acc[4], 0, 0, 0);
    }

    // epilogue: C layout col=lane&15, row=(lane>>4)*4+r
    const int crow = row0 + lg * 4;
    const int ccol = half * NHALF + cg * 80 + lr;
#pragma unroll
    for (int j = 0; j < 5; ++j)
#pragma unroll
        for (int r = 0; r < 4; ++r)
            C[(size_t)(crow + r) * QK_N + ccol + j * 16] = f2bf(acc[j][r]);
}

// ---------------- scores: I[b,t,s] = sum_h w[h]*relu(Q_h K^T) ----------------
// grid (32,32,2); block 256 = 4 waves (2x2). block tile 128x128, wave tile 64x64.
// MFMA operands swapped (a=K-frag, b=Q-frag) so each lane's 4 acc regs are 4
// consecutive s values -> float4 stores.
__global__ __launch_bounds__(256) void scores_kernel(
    const unsigned short* __restrict__ QK,   // [B][4096][320] bf16
    const float* __restrict__ w,             // [4]
    float* __restrict__ out)                 // [B][4096][4096] fp32
{
    const int lane = threadIdx.x & 63;
    const int wid  = threadIdx.x >> 6;
    const int b  = blockIdx.z;
    const int t0 = blockIdx.y * 128 + (wid >> 1) * 64;
    const int s0 = blockIdx.x * 128 + (wid & 1) * 64;

    const int lr = lane & 15;
    const int lk = (lane >> 4) * 8;
    const int lg = lane >> 4;

    const unsigned short* Qb = QK + (size_t)b * SEQ * QK_N;
    const unsigned short* Kb = Qb + 256;

    float wv[4] = { w[0], w[1], w[2], w[3] };

    f32x4 fin[4][4];
#pragma unroll
    for (int i = 0; i < 4; ++i)
#pragma unroll
        for (int j = 0; j < 4; ++j) fin[i][j] = (f32x4)0.f;

    const unsigned short* qp = Qb + (size_t)(t0 + lr) * QK_N + lk;
    const unsigned short* kp = Kb + (size_t)(s0 + lr) * QK_N + lk;

#pragma unroll
    for (int h = 0; h < 4; ++h) {
        f32x4 acc[4][4];
#pragma unroll
        for (int i = 0; i < 4; ++i)
#pragma unroll
            for (int j = 0; j < 4; ++j) acc[i][j] = (f32x4)0.f;

#pragma unroll
        for (int ks = 0; ks < 2; ++ks) {
            bf16x8 qf[4], kf[4];
#pragma unroll
            for (int i = 0; i < 4; ++i)
                qf[i] = *reinterpret_cast<const bf16x8*>(
                    qp + (size_t)i * 16 * QK_N + h * 64 + ks * 32);
#pragma unroll
            for (int j = 0; j < 4; ++j)
                kf[j] = *reinterpret_cast<const bf16x8*>(
                    kp + (size_t)j * 16 * QK_N + ks * 32);
            // swapped: a=K (s in reg dim), b=Q (t on lane&15)
#pragma unroll
            for (int i = 0; i < 4; ++i)
#pragma unroll
                for (int j = 0; j < 4; ++j)
                    acc[i][j] = __builtin_amdgcn_mfma_f32_16x16x32_bf16(kf[j], qf[i], acc[i][j], 0, 0, 0);
        }
#pragma unroll
        for (int i = 0; i < 4; ++i)
#pragma unroll
            for (int j = 0; j < 4; ++j)
#pragma unroll
                for (int r = 0; r < 4; ++r)
                    fin[i][j][r] += wv[h] * fmaxf(acc[i][j][r], 0.f);
    }

    // store: lane holds t = t0+i*16+lr, s = s0+j*16+lg*4 .. +3 (contiguous)
    float* ob = out + (size_t)b * SEQ * SEQ;
#pragma unroll
    for (int i = 0; i < 4; ++i) {
        const size_t rbase = (size_t)(t0 + i * 16 + lr) * SEQ + s0 + lg * 4;
#pragma unroll
        for (int j = 0; j < 4; ++j) {
            float4 v;
            v.x = fin[i][j][0]; v.y = fin[i][j][1];
            v.z = fin[i][j][2]; v.w = fin[i][j][3];
            *reinterpret_cast<float4*>(&ob[rbase + j * 16]) = v;
        }
    }
}

// ---------------- launch ----------------
extern "C" void kernel_launch(void* const* d_in, const int* in_sizes, int n_in,
                              void* d_out, int out_size, void* d_ws, size_t ws_size,
                              hipStream_t stream) {
    const float* h  = (const float*)d_in[0];   // [2,4096,2048]
    const float* Wq = (const float*)d_in[1];   // [256,2048]
    const float* Wk = (const float*)d_in[2];   // [64,2048]
    const float* w  = (const float*)d_in[3];   // [4]
    float* out = (float*)d_out;                // [2,4096,4096]

    unsigned short* W_swz = (unsigned short*)d_ws;                 // 2 x 32 x 20KB = 1.25MB
    unsigned short* QKb   = (unsigned short*)((char*)d_ws + 2 * (size_t)NCHUNK * BCHUNK);

    cvt_w_swz<<<320, 256, 0, stream>>>(Wq, Wk, W_swz);
    proj_gemm<<<dim3(2, 256), 256, 0, stream>>>(h, W_swz, QKb);
    scores_kernel<<<dim3(32, 32, 2), 256, 0, stream>>>(QKb, w, out);
}

// Round 7
// 124.094 us; speedup vs baseline: 1.0020x; 1.0020x over previous
//
#include <hip/hip_runtime.h>

// ---------------- types ----------------
typedef __attribute__((ext_vector_type(8))) short bf16x8;   // 8 bf16 in 4 VGPRs
typedef __attribute__((ext_vector_type(4))) float f32x4;
typedef __attribute__((ext_vector_type(8))) unsigned short us8;
typedef __attribute__((ext_vector_type(4))) unsigned short us4;

#define K_DIM 2048
#define QK_N  320     // 256 q cols + 64 k cols
#define SEQ   4096
#define BK    64
#define NCHUNK 32                      // K_DIM / BK
#define NHALF  160                     // N columns per block
#define BCHUNK 20480                   // bytes of one B chunk: 8 units * 160 cols * 16B
#define KSPLIT 2
#define SEGCHUNK (NCHUNK / KSPLIT)     // 16 chunks per k-segment
#define CPART_ELEMS ((size_t)8192 * QK_N)   // fp32 elems per segment

__device__ __forceinline__ unsigned short f2bf(float f) {
    unsigned int u = __builtin_bit_cast(unsigned int, f);
    u += 0x7FFFu + ((u >> 16) & 1u);      // round-to-nearest-even
    return (unsigned short)(u >> 16);
}

// ---------------- W convert + re-layout ----------------
// ws layout: [2 N-halves][NCHUNK][8 k-units][160 cols][16B]
__global__ void cvt_w_swz(const float* __restrict__ Wq,
                          const float* __restrict__ Wk,
                          unsigned short* __restrict__ ws) {
    int id = blockIdx.x * 256 + threadIdx.x;   // 320*256 ids
    int c  = id >> 8;                          // 0..319 (output col)
    int k8 = id & 255;                         // 8-elem k group
    int k0 = k8 * 8;
    const float* src = (c < 256) ? (Wq + (size_t)c * K_DIM + k0)
                                 : (Wk + (size_t)(c - 256) * K_DIM + k0);
    float4 v0 = *reinterpret_cast<const float4*>(src);
    float4 v1 = *reinterpret_cast<const float4*>(src + 4);
    us8 o;
    o[0] = f2bf(v0.x); o[1] = f2bf(v0.y); o[2] = f2bf(v0.z); o[3] = f2bf(v0.w);
    o[4] = f2bf(v1.x); o[5] = f2bf(v1.y); o[6] = f2bf(v1.z); o[7] = f2bf(v1.w);
    int half = (c >= NHALF) ? 1 : 0;
    int cc   = c - half * NHALF;
    int kc = k0 / BK;            // chunk index 0..31
    int u  = (k0 % BK) >> 3;     // k-unit within chunk (0..7)
    size_t byteoff = (size_t)half * (NCHUNK * (size_t)BCHUNK)
                   + (size_t)kc * BCHUNK + ((size_t)(u * NHALF + cc) * 16);
    *reinterpret_cast<us8*>((char*)ws + byteoff) = o;
}

// ---------------- projection GEMM, split-K=2, fp32 partials ----------------
// grid (2 N-halves, 256 M-strips, 2 k-segments) = 1024 blocks x 256 threads
// (4 waves: 2 rg x 2 cg). block tile 32x160 over K=1024. No LDS, no barriers;
// explicit 1-deep register double-buffer so ~12 loads stay in flight per wave.
__global__ __launch_bounds__(256, 4) void proj_gemm(
    const float* __restrict__ A,            // h fp32 [8192][2048]
    const unsigned short* __restrict__ Wsz, // re-laid-out W
    float* __restrict__ Cpart)              // [KSPLIT][8192][320] fp32
{
    const int tid  = threadIdx.x;
    const int lane = tid & 63;
    const int wid  = tid >> 6;          // 0..3
    const int rg   = wid >> 1;          // 0..1 (M row-group)
    const int cg   = wid & 1;           // 0..1 (N col-group)
    const int half = blockIdx.x;
    const int kseg = blockIdx.z;
    const int row0 = blockIdx.y * 32 + rg * 16;
    const int lr = lane & 15, lg = lane >> 4;

    const float* ap = A + (size_t)(row0 + lr) * K_DIM + kseg * (K_DIM / KSPLIT) + lg * 8;
    const char* wbase = (const char*)Wsz + (size_t)half * (NCHUNK * (size_t)BCHUNK)
                      + (size_t)(kseg * SEGCHUNK) * BCHUNK
                      + ((cg * 80 + lr) << 4);

    f32x4 acc[5];
#pragma unroll
    for (int j = 0; j < 5; ++j) acc[j] = (f32x4)0.f;

#define LOADB(t, b0, b1, b2, b3, b4) do {                                   \
        const char* bu = wbase + (size_t)((t) >> 1) * BCHUNK                \
                       + (size_t)((((t) & 1) * 4 + lg) * NHALF) * 16;       \
        b0 = *reinterpret_cast<const bf16x8*>(bu);                          \
        b1 = *reinterpret_cast<const bf16x8*>(bu + 256);                    \
        b2 = *reinterpret_cast<const bf16x8*>(bu + 512);                    \
        b3 = *reinterpret_cast<const bf16x8*>(bu + 768);                    \
        b4 = *reinterpret_cast<const bf16x8*>(bu + 1024);                   \
    } while (0)
#define LOADA(t, vx, vy) do {                                               \
        const float* p = ap + (t) * 32;                                     \
        vx = *reinterpret_cast<const float4*>(p);                           \
        vy = *reinterpret_cast<const float4*>(p + 4);                       \
    } while (0)
#define COMPUTE(vx, vy, b0, b1, b2, b3, b4) do {                            \
        bf16x8 a_;                                                          \
        a_[0] = (short)f2bf(vx.x); a_[1] = (short)f2bf(vx.y);               \
        a_[2] = (short)f2bf(vx.z); a_[3] = (short)f2bf(vx.w);               \
        a_[4] = (short)f2bf(vy.x); a_[5] = (short)f2bf(vy.y);               \
        a_[6] = (short)f2bf(vy.z); a_[7] = (short)f2bf(vy.w);               \
        acc[0] = __builtin_amdgcn_mfma_f32_16x16x32_bf16(a_, b0, acc[0], 0, 0, 0); \
        acc[1] = __builtin_amdgcn_mfma_f32_16x16x32_bf16(a_, b1, acc[1], 0, 0, 0); \
        acc[2] = __builtin_amdgcn_mfma_f32_16x16x32_bf16(a_, b2, acc[2], 0, 0, 0); \
        acc[3] = __builtin_amdgcn_mfma_f32_16x16x32_bf16(a_, b3, acc[3], 0, 0, 0); \
        acc[4] = __builtin_amdgcn_mfma_f32_16x16x32_bf16(a_, b4, acc[4], 0, 0, 0); \
    } while (0)

    // ping-pong register sets (static names — rule #20)
    bf16x8 cb0, cb1, cb2, cb3, cb4;  float4 cvx, cvy;
    bf16x8 nb0, nb1, nb2, nb3, nb4;  float4 nvx, nvy;

    LOADB(0, cb0, cb1, cb2, cb3, cb4);
    LOADA(0, cvx, cvy);

    for (int t = 0; t < 32; t += 2) {
        // issue t+1 loads, then compute t
        LOADB(t + 1, nb0, nb1, nb2, nb3, nb4);
        LOADA(t + 1, nvx, nvy);
        COMPUTE(cvx, cvy, cb0, cb1, cb2, cb3, cb4);
        // issue t+2 loads (clamped), then compute t+1
        const int t2 = (t + 2 < 32) ? t + 2 : 31;
        LOADB(t2, cb0, cb1, cb2, cb3, cb4);
        LOADA(t2, cvx, cvy);
        COMPUTE(nvx, nvy, nb0, nb1, nb2, nb3, nb4);
    }
#undef LOADB
#undef LOADA
#undef COMPUTE

    // epilogue: partial fp32 tile (unique per kseg — plain stores)
    float* cp = Cpart + (size_t)kseg * CPART_ELEMS;
    const int crow = row0 + lg * 4;
    const int ccol = half * NHALF + cg * 80 + lr;
#pragma unroll
    for (int j = 0; j < 5; ++j)
#pragma unroll
        for (int r = 0; r < 4; ++r)
            cp[(size_t)(crow + r) * QK_N + ccol + j * 16] = acc[j][r];
}

// ---------------- reduce partials + cvt to bf16 ----------------
__global__ void reduce_cvt(const float* __restrict__ Cpart,
                           unsigned short* __restrict__ QKb) {
    int i = blockIdx.x * 256 + threadIdx.x;    // float4 index, 655360 total
    float4 a = reinterpret_cast<const float4*>(Cpart)[i];
    float4 b = reinterpret_cast<const float4*>(Cpart + CPART_ELEMS)[i];
    us4 o;
    o[0] = f2bf(a.x + b.x); o[1] = f2bf(a.y + b.y);
    o[2] = f2bf(a.z + b.z); o[3] = f2bf(a.w + b.w);
    reinterpret_cast<us4*>(QKb)[i] = o;
}

// ---------------- scores: I[b,t,s] = sum_h w[h]*relu(Q_h K^T) ----------------
// grid (32,32,2); block 256 = 4 waves (2x2). block tile 128x128, wave tile 64x64.
// MFMA operands swapped (a=K-frag, b=Q-frag) so each lane's 4 acc regs are 4
// consecutive s values -> float4 stores.
__global__ __launch_bounds__(256) void scores_kernel(
    const unsigned short* __restrict__ QK,   // [B][4096][320] bf16
    const float* __restrict__ w,             // [4]
    float* __restrict__ out)                 // [B][4096][4096] fp32
{
    const int lane = threadIdx.x & 63;
    const int wid  = threadIdx.x >> 6;
    const int b  = blockIdx.z;
    const int t0 = blockIdx.y * 128 + (wid >> 1) * 64;
    const int s0 = blockIdx.x * 128 + (wid & 1) * 64;

    const int lr = lane & 15;
    const int lk = (lane >> 4) * 8;
    const int lg = lane >> 4;

    const unsigned short* Qb = QK + (size_t)b * SEQ * QK_N;
    const unsigned short* Kb = Qb + 256;

    float wv[4] = { w[0], w[1], w[2], w[3] };

    f32x4 fin[4][4];
#pragma unroll
    for (int i = 0; i < 4; ++i)
#pragma unroll
        for (int j = 0; j < 4; ++j) fin[i][j] = (f32x4)0.f;

    const unsigned short* qp = Qb + (size_t)(t0 + lr) * QK_N + lk;
    const unsigned short* kp = Kb + (size_t)(s0 + lr) * QK_N + lk;

#pragma unroll
    for (int h = 0; h < 4; ++h) {
        f32x4 acc[4][4];
#pragma unroll
        for (int i = 0; i < 4; ++i)
#pragma unroll
            for (int j = 0; j < 4; ++j) acc[i][j] = (f32x4)0.f;

#pragma unroll
        for (int ks = 0; ks < 2; ++ks) {
            bf16x8 qf[4], kf[4];
#pragma unroll
            for (int i = 0; i < 4; ++i)
                qf[i] = *reinterpret_cast<const bf16x8*>(
                    qp + (size_t)i * 16 * QK_N + h * 64 + ks * 32);
#pragma unroll
            for (int j = 0; j < 4; ++j)
                kf[j] = *reinterpret_cast<const bf16x8*>(
                    kp + (size_t)j * 16 * QK_N + ks * 32);
            // swapped: a=K (s in reg dim), b=Q (t on lane&15)
#pragma unroll
            for (int i = 0; i < 4; ++i)
#pragma unroll
                for (int j = 0; j < 4; ++j)
                    acc[i][j] = __builtin_amdgcn_mfma_f32_16x16x32_bf16(kf[j], qf[i], acc[i][j], 0, 0, 0);
        }
#pragma unroll
        for (int i = 0; i < 4; ++i)
#pragma unroll
            for (int j = 0; j < 4; ++j)
#pragma unroll
                for (int r = 0; r < 4; ++r)
                    fin[i][j][r] += wv[h] * fmaxf(acc[i][j][r], 0.f);
    }

    // store: lane holds t = t0+i*16+lr, s = s0+j*16+lg*4 .. +3 (contiguous)
    float* ob = out + (size_t)b * SEQ * SEQ;
#pragma unroll
    for (int i = 0; i < 4; ++i) {
        const size_t rbase = (size_t)(t0 + i * 16 + lr) * SEQ + s0 + lg * 4;
#pragma unroll
        for (int j = 0; j < 4; ++j) {
            float4 v;
            v.x = fin[i][j][0]; v.y = fin[i][j][1];
            v.z = fin[i][j][2]; v.w = fin[i][j][3];
            *reinterpret_cast<float4*>(&ob[rbase + j * 16]) = v;
        }
    }
}

// ---------------- launch ----------------
extern "C" void kernel_launch(void* const* d_in, const int* in_sizes, int n_in,
                              void* d_out, int out_size, void* d_ws, size_t ws_size,
                              hipStream_t stream) {
    const float* h  = (const float*)d_in[0];   // [2,4096,2048]
    const float* Wq = (const float*)d_in[1];   // [256,2048]
    const float* Wk = (const float*)d_in[2];   // [64,2048]
    const float* w  = (const float*)d_in[3];   // [4]
    float* out = (float*)d_out;                // [2,4096,4096]

    char* ws = (char*)d_ws;
    unsigned short* W_swz = (unsigned short*)ws;                       // 1.25 MB
    ws += 2 * (size_t)NCHUNK * BCHUNK;
    unsigned short* QKb = (unsigned short*)ws;                         // 5 MB bf16
    ws += (size_t)8192 * QK_N * 2;
    float* Cpart = (float*)ws;                                         // 2 x 10 MB fp32

    cvt_w_swz<<<320, 256, 0, stream>>>(Wq, Wk, W_swz);
    proj_gemm<<<dim3(2, 256, KSPLIT), 256, 0, stream>>>(h, W_swz, Cpart);
    reduce_cvt<<<(int)(CPART_ELEMS / 4 / 256), 256, 0, stream>>>(Cpart, QKb);
    scores_kernel<<<dim3(32, 32, 2), 256, 0, stream>>>(QKb, w, out);
}